// Round 1
// baseline (140.555 us; speedup 1.0000x reference)
//
#include <hip/hip_runtime.h>

#define EPS 1e-8f

// ---------------------------------------------------------------------------
// Output layout (floats):
//   [0,        65536)      concrete_lower  [64,1024]
//   [65536,    131072)     concrete_upper  [64,1024]
//   [131072,   67239936)   lower_coef      [64,1024,1024] (diag only)
//   [67239936, 134348800)  upper_coef      [64,1024,1024] (diag only)
//   [134348800,134414336)  lower_bias      [64,1024] (zeros)
//   [134414336,134479872)  upper_bias      [64,1024] (mu_upper)
// ---------------------------------------------------------------------------

__global__ void small_outs_kernel(const float* __restrict__ lower,
                                  const float* __restrict__ upper,
                                  float* __restrict__ out) {
    const int BN = 64 * 1024;
    int idx = blockIdx.x * blockDim.x + threadIdx.x;
    if (idx >= BN) return;
    float l = lower[idx];
    float u = upper[idx];
    float cl = fmaxf(l, 0.0f);
    float cu = fmaxf(u, 0.0f);
    bool crossing = (l < 0.0f) && (u > 0.0f);
    float lam = crossing ? u / (u - l + EPS) : 0.0f;
    float mu  = crossing ? -lam * l : 0.0f;
    const long long off_bias = 2LL * BN + 2LL * 64 * 1024 * 1024;  // 134348800
    out[idx]                 = cl;    // concrete_lower
    out[BN + idx]            = cu;    // concrete_upper
    out[off_bias + idx]      = 0.0f;  // lower_bias
    out[off_bias + BN + idx] = mu;    // upper_bias
}

// Fills BOTH coef tensors (contiguous: lower_coef then upper_coef) with
// zeros + diagonal values, as float4 streaming stores.
__global__ void coef_kernel(const float* __restrict__ lower,
                            const float* __restrict__ upper,
                            float4* __restrict__ coef) {
    const int TOTAL_VEC = 33554432;   // 2 * 64*1024*1024 floats / 4
    const int BN = 65536;             // 64*1024 rows per coef tensor
    int stride = gridDim.x * blockDim.x;
    for (int idx = blockIdx.x * blockDim.x + threadIdx.x; idx < TOTAL_VEC;
         idx += stride) {
        int row  = idx >> 8;          // 256 float4 per 1024-wide row
        int col4 = idx & 255;
        float4 z = {0.0f, 0.0f, 0.0f, 0.0f};
        int rr = row & (BN - 1);      // flat (b, i) index into [64,1024]
        int i  = rr & 1023;           // neuron index => diagonal column
        if ((i >> 2) == col4) {       // this thread's float4 holds the diagonal
            float l = lower[rr];
            bool active = (l >= 0.0f);
            float v;
            if (row < BN) {
                // lower_diag: 1 if active else 0
                v = active ? 1.0f : 0.0f;
            } else {
                // upper_diag: 1 if active else lambda_upper
                float u = upper[rr];
                bool crossing = (l < 0.0f) && (u > 0.0f);
                float lam = crossing ? u / (u - l + EPS) : 0.0f;
                v = active ? 1.0f : lam;
            }
            ((float*)&z)[i & 3] = v;
        }
        coef[idx] = z;
    }
}

extern "C" void kernel_launch(void* const* d_in, const int* in_sizes, int n_in,
                              void* d_out, int out_size, void* d_ws, size_t ws_size,
                              hipStream_t stream) {
    const float* lower = (const float*)d_in[0];
    const float* upper = (const float*)d_in[1];
    float* out = (float*)d_out;

    // Four small [64,1024] outputs.
    small_outs_kernel<<<256, 256, 0, stream>>>(lower, upper, out);

    // The two dense diagonal tensors: 537 MB of float4 streaming stores.
    coef_kernel<<<2048, 256, 0, stream>>>(lower, upper,
                                          (float4*)(out + 131072));
}

// Round 3
// 130.898 us; speedup vs baseline: 1.0738x; 1.0738x over previous
//
#include <hip/hip_runtime.h>

#define EPS 1e-8f

typedef float f32x4 __attribute__((ext_vector_type(4)));

// ---------------------------------------------------------------------------
// Output layout (floats):
//   [0,        65536)      concrete_lower  [64,1024]
//   [65536,    131072)     concrete_upper  [64,1024]
//   [131072,   67239936)   lower_coef      [64,1024,1024] (diag only)
//   [67239936, 134348800)  upper_coef      [64,1024,1024] (diag only)
//   [134348800,134414336)  lower_bias      [64,1024] (zeros)
//   [134414336,134479872)  upper_bias      [64,1024] (mu_upper)
// ---------------------------------------------------------------------------

__global__ void small_outs_kernel(const float* __restrict__ lower,
                                  const float* __restrict__ upper,
                                  float* __restrict__ out) {
    const int BN = 64 * 1024;
    int idx = blockIdx.x * blockDim.x + threadIdx.x;
    if (idx >= BN) return;
    float l = lower[idx];
    float u = upper[idx];
    float cl = fmaxf(l, 0.0f);
    float cu = fmaxf(u, 0.0f);
    bool crossing = (l < 0.0f) && (u > 0.0f);
    float lam = crossing ? u / (u - l + EPS) : 0.0f;
    float mu  = crossing ? -lam * l : 0.0f;
    const long long off_bias = 2LL * BN + 2LL * 64 * 1024 * 1024;  // 134348800
    __builtin_nontemporal_store(cl,   out + idx);                  // concrete_lower
    __builtin_nontemporal_store(cu,   out + BN + idx);             // concrete_upper
    __builtin_nontemporal_store(0.0f, out + off_bias + idx);       // lower_bias
    __builtin_nontemporal_store(mu,   out + off_bias + BN + idx);  // upper_bias
}

// Fills BOTH coef tensors (contiguous: lower_coef then upper_coef) with
// zeros + diagonal values, as non-temporal float4 streaming stores.
__global__ void coef_kernel(const float* __restrict__ lower,
                            const float* __restrict__ upper,
                            f32x4* __restrict__ coef) {
    const int TOTAL_VEC = 33554432;   // 2 * 64*1024*1024 floats / 4
    const int BN = 65536;             // 64*1024 rows per coef tensor
    int stride = gridDim.x * blockDim.x;
    for (int idx = blockIdx.x * blockDim.x + threadIdx.x; idx < TOTAL_VEC;
         idx += stride) {
        int row  = idx >> 8;          // 256 float4 per 1024-wide row
        int col4 = idx & 255;
        f32x4 z = {0.0f, 0.0f, 0.0f, 0.0f};
        int rr = row & (BN - 1);      // flat (b, i) index into [64,1024]
        int i  = rr & 1023;           // neuron index => diagonal column
        if ((i >> 2) == col4) {       // this thread's float4 holds the diagonal
            float l = lower[rr];
            bool active = (l >= 0.0f);
            float v;
            if (row < BN) {
                // lower_diag: 1 if active else 0
                v = active ? 1.0f : 0.0f;
            } else {
                // upper_diag: 1 if active else lambda_upper
                float u = upper[rr];
                bool crossing = (l < 0.0f) && (u > 0.0f);
                float lam = crossing ? u / (u - l + EPS) : 0.0f;
                v = active ? 1.0f : lam;
            }
            z[i & 3] = v;
        }
        __builtin_nontemporal_store(z, coef + idx);
    }
}

extern "C" void kernel_launch(void* const* d_in, const int* in_sizes, int n_in,
                              void* d_out, int out_size, void* d_ws, size_t ws_size,
                              hipStream_t stream) {
    const float* lower = (const float*)d_in[0];
    const float* upper = (const float*)d_in[1];
    float* out = (float*)d_out;

    // Four small [64,1024] outputs.
    small_outs_kernel<<<256, 256, 0, stream>>>(lower, upper, out);

    // The two dense diagonal tensors: 537 MB of non-temporal float4 stores.
    coef_kernel<<<2048, 256, 0, stream>>>(lower, upper,
                                          (f32x4*)(out + 131072));
}

// Round 4
// 122.086 us; speedup vs baseline: 1.1513x; 1.0722x over previous
//
#include <hip/hip_runtime.h>

#define EPS 1e-8f

typedef float f32x4 __attribute__((ext_vector_type(4)));

// ---------------------------------------------------------------------------
// Output layout (floats):
//   [0,        65536)      concrete_lower  [64,1024]
//   [65536,    131072)     concrete_upper  [64,1024]
//   [131072,   67239936)   lower_coef      [64,1024,1024] (diag only)
//   [67239936, 134348800)  upper_coef      [64,1024,1024] (diag only)
//   [134348800,134414336)  lower_bias      [64,1024] (zeros)
//   [134414336,134479872)  upper_bias      [64,1024] (mu_upper)
//
// Strategy: one pure streaming-fill kernel zeroes [131072, 134414336)
// (both coef tensors + lower_bias, contiguous) at fill-kernel speed; a
// second tiny kernel scatters the 131072 diagonal values and computes the
// four small outputs.
// ---------------------------------------------------------------------------

__global__ void fill_zero_kernel(f32x4* __restrict__ dst, int total_vec) {
    const int stride = gridDim.x * blockDim.x;
    const f32x4 z = {0.0f, 0.0f, 0.0f, 0.0f};
#pragma unroll 4
    for (int i = blockIdx.x * blockDim.x + threadIdx.x; i < total_vec;
         i += stride) {
        __builtin_nontemporal_store(z, dst + i);
    }
}

__global__ void diag_small_kernel(const float* __restrict__ lower,
                                  const float* __restrict__ upper,
                                  float* __restrict__ out) {
    const int BN = 65536;  // 64*1024
    int t = blockIdx.x * blockDim.x + threadIdx.x;
    if (t >= 2 * BN) return;
    int rr = t & (BN - 1);       // flat (b, i) index into [64,1024]
    int i  = rr & 1023;          // neuron index => diagonal column
    float l = lower[rr];
    float u = upper[rr];
    bool active   = (l >= 0.0f);
    bool crossing = (l < 0.0f) && (u > 0.0f);
    float lam = crossing ? u / (u - l + EPS) : 0.0f;

    // Diagonal element of lower_coef (t < BN) or upper_coef (t >= BN).
    // Row t of the concatenated [131072, 1024] coef block.
    float v = active ? 1.0f : (t < BN ? 0.0f : lam);
    if (v != 0.0f) {
        out[131072LL + (long long)t * 1024 + i] = v;
    }

    if (t < BN) {
        float mu = crossing ? -lam * l : 0.0f;
        out[t]                  = fmaxf(l, 0.0f);   // concrete_lower
        out[BN + t]             = fmaxf(u, 0.0f);   // concrete_upper
        out[134414336LL + t]    = mu;               // upper_bias
        // lower_bias zeros are covered by fill_zero_kernel.
    }
}

extern "C" void kernel_launch(void* const* d_in, const int* in_sizes, int n_in,
                              void* d_out, int out_size, void* d_ws, size_t ws_size,
                              hipStream_t stream) {
    const float* lower = (const float*)d_in[0];
    const float* upper = (const float*)d_in[1];
    float* out = (float*)d_out;

    // Zero both coef tensors + lower_bias: floats [131072, 134414336)
    //  = 134283264 floats = 33570816 float4s.
    fill_zero_kernel<<<2048, 256, 0, stream>>>((f32x4*)(out + 131072),
                                               33570816);

    // Scatter diagonals + small outputs (runs after fill on same stream).
    diag_small_kernel<<<512, 256, 0, stream>>>(lower, upper, out);
}

// Round 5
// 109.313 us; speedup vs baseline: 1.2858x; 1.1169x over previous
//
#include <hip/hip_runtime.h>

#define EPS 1e-8f

typedef float f32x4 __attribute__((ext_vector_type(4)));

// ---------------------------------------------------------------------------
// Output layout (floats):
//   [0,        65536)      concrete_lower  [64,1024]
//   [65536,    131072)     concrete_upper  [64,1024]
//   [131072,   67239936)   lower_coef      [64,1024,1024] (diag only)
//   [67239936, 134348800)  upper_coef      [64,1024,1024] (diag only)
//   [134348800,134414336)  lower_bias      [64,1024] (zeros)
//   [134414336,134479872)  upper_bias      [64,1024] (mu_upper)
//
// Zero region: floats [131072, 134414336) = 134283264 floats
//            = 33570816 float4 = 256 blocks * 131136 float4/block (exact).
// Low-occupancy streaming fill: 1 block/CU, each block writes its own
// contiguous 2.1 MB region front-to-back (4 KB per iteration, coalesced
// 1 KB nt wave-stores) to minimize concurrent DRAM write streams.
// ---------------------------------------------------------------------------

__global__ void __launch_bounds__(256, 1)
fill_zero_kernel(f32x4* __restrict__ dst) {
    const int PER_BLOCK = 131136;      // 33570816 / 256, = 256*512 + 64
    f32x4* base = dst + (size_t)blockIdx.x * PER_BLOCK;
    const f32x4 z = {0.0f, 0.0f, 0.0f, 0.0f};
    int tid = threadIdx.x;
#pragma unroll 8
    for (int i = 0; i < 512; ++i) {
        __builtin_nontemporal_store(z, base + i * 256 + tid);
    }
    if (tid < 64) {
        __builtin_nontemporal_store(z, base + 512 * 256 + tid);
    }
}

__global__ void diag_small_kernel(const float* __restrict__ lower,
                                  const float* __restrict__ upper,
                                  float* __restrict__ out) {
    const int BN = 65536;  // 64*1024
    int t = blockIdx.x * blockDim.x + threadIdx.x;
    if (t >= 2 * BN) return;
    int rr = t & (BN - 1);       // flat (b, i) index into [64,1024]
    int i  = rr & 1023;          // neuron index => diagonal column
    float l = lower[rr];
    float u = upper[rr];
    bool active   = (l >= 0.0f);
    bool crossing = (l < 0.0f) && (u > 0.0f);
    float lam = crossing ? u / (u - l + EPS) : 0.0f;

    // Diagonal element of lower_coef (t < BN) or upper_coef (t >= BN).
    float v = active ? 1.0f : (t < BN ? 0.0f : lam);
    if (v != 0.0f) {
        out[131072LL + (long long)t * 1024 + i] = v;
    }

    if (t < BN) {
        float mu = crossing ? -lam * l : 0.0f;
        out[t]                  = fmaxf(l, 0.0f);   // concrete_lower
        out[BN + t]             = fmaxf(u, 0.0f);   // concrete_upper
        out[134414336LL + t]    = mu;               // upper_bias
        // lower_bias zeros covered by fill_zero_kernel.
    }
}

extern "C" void kernel_launch(void* const* d_in, const int* in_sizes, int n_in,
                              void* d_out, int out_size, void* d_ws, size_t ws_size,
                              hipStream_t stream) {
    const float* lower = (const float*)d_in[0];
    const float* upper = (const float*)d_in[1];
    float* out = (float*)d_out;

    // Zero both coef tensors + lower_bias: floats [131072, 134414336).
    fill_zero_kernel<<<256, 256, 0, stream>>>((f32x4*)(out + 131072));

    // Scatter diagonals + small outputs (runs after fill on same stream).
    diag_small_kernel<<<512, 256, 0, stream>>>(lower, upper, out);
}

// Round 6
// 102.258 us; speedup vs baseline: 1.3745x; 1.0690x over previous
//
#include <hip/hip_runtime.h>

#define EPS 1e-8f

// ---------------------------------------------------------------------------
// Output layout (floats):
//   [0,        65536)      concrete_lower  [64,1024]
//   [65536,    131072)     concrete_upper  [64,1024]
//   [131072,   67239936)   lower_coef      [64,1024,1024] (diag only)
//   [67239936, 134348800)  upper_coef      [64,1024,1024] (diag only)
//   [134348800,134414336)  lower_bias     [64,1024] (zeros)
//   [134414336,134479872)  upper_bias     [64,1024] (mu_upper)
//
// Strategy: hipMemsetAsync zeroes the contiguous region [131072, 134414336)
// (both coef tensors + lower_bias) using the rocclr fillBufferAligned path
// (measured 6.5-6.7 TB/s on this exact size class every round); then a tiny
// kernel scatters the 131072 diagonal values and the four small outputs.
// ---------------------------------------------------------------------------

__global__ void diag_small_kernel(const float* __restrict__ lower,
                                  const float* __restrict__ upper,
                                  float* __restrict__ out) {
    const int BN = 65536;  // 64*1024
    int t = blockIdx.x * blockDim.x + threadIdx.x;
    if (t >= 2 * BN) return;
    int rr = t & (BN - 1);       // flat (b, i) index into [64,1024]
    int i  = rr & 1023;          // neuron index => diagonal column
    float l = lower[rr];
    float u = upper[rr];
    bool active   = (l >= 0.0f);
    bool crossing = (l < 0.0f) && (u > 0.0f);
    float lam = crossing ? u / (u - l + EPS) : 0.0f;

    // Diagonal element of lower_coef (t < BN) or upper_coef (t >= BN).
    float v = active ? 1.0f : (t < BN ? 0.0f : lam);
    if (v != 0.0f) {
        out[131072LL + (long long)t * 1024 + i] = v;
    }

    if (t < BN) {
        float mu = crossing ? -lam * l : 0.0f;
        out[t]                  = fmaxf(l, 0.0f);   // concrete_lower
        out[BN + t]             = fmaxf(u, 0.0f);   // concrete_upper
        out[134414336LL + t]    = mu;               // upper_bias
        // lower_bias zeros covered by the memset.
    }
}

extern "C" void kernel_launch(void* const* d_in, const int* in_sizes, int n_in,
                              void* d_out, int out_size, void* d_ws, size_t ws_size,
                              hipStream_t stream) {
    const float* lower = (const float*)d_in[0];
    const float* upper = (const float*)d_in[1];
    float* out = (float*)d_out;

    // Zero both coef tensors + lower_bias: floats [131072, 134414336)
    //  = 134283264 floats = 537,133,056 bytes.
    hipMemsetAsync(out + 131072, 0, 134283264ULL * sizeof(float), stream);

    // Scatter diagonals + small outputs (after memset on same stream).
    diag_small_kernel<<<512, 256, 0, stream>>>(lower, upper, out);
}